// Round 19
// baseline (25.131 us; speedup 1.0000x reference)
//
#include <hip/hip_runtime.h>
#include <math.h>

#define B_ 8
#define S_ 2048
#define D_ 128
#define K_ 64
#define SIG_ 0.5f
#define EPS_ 10.0f
#define E_ 2.718281828459045f

// XCD-aware remaps: HW round-robins blockIdx over 8 XCDs; batch == XCD.
__device__ __forceinline__ int remap256(int bx) { return ((bx & 7) << 5) | (bx >> 3); }

// ---------------- Fused dispatch 1: 512 blocks x 512 threads.
// Blocks 0..255  (kpre): k1-INDEPENDENT heavy half: stage Cs+Ft (+co-op csq),
//   phase B centroid GEMM, sq self-dot, cd2 -> {s_cd, pos_cent}; writes pre[].
// Blocks 256..511 (k1'): class stats for 2 classes per block (ballot+gather).
// Block 0 also zeroes out[0] (k_post accumulates into it atomically).
__global__ void __launch_bounds__(512) fused1(
    const float* __restrict__ F, const float* __restrict__ C,
    const float* __restrict__ phi, const int* __restrict__ L,
    float* __restrict__ fsumK, float* __restrict__ ssumK, float* __restrict__ cntK,
    float* __restrict__ pre, float* __restrict__ out) {

    int tid = threadIdx.x;

    if (blockIdx.x < 256) {
        // ================= kpre =================
        __shared__ float Cs[K_ * 129];   // conflict-free b32 column reads
        __shared__ float Ft[64 * D_];    // block 64-anchor F-tile
        __shared__ float csqS[K_];
        int bxw = remap256(blockIdx.x);

        if (blockIdx.x == 0 && tid == 0) out[0] = 0.f;   // reset accumulator

        {   // stage centroids + co-op csq (32-thread groups share a centroid)
            const float4* C4 = (const float4*)C;
            #pragma unroll
            for (int it = 0; it < 4; ++it) {
                int i = it * 512 + tid;
                float4 v = C4[i];
                float* p = &Cs[(i >> 5) * 129 + ((i & 31) << 2)];
                p[0] = v.x; p[1] = v.y; p[2] = v.z; p[3] = v.w;
                float d2 = fmaf(v.x, v.x, fmaf(v.y, v.y, fmaf(v.z, v.z, v.w * v.w)));
                #pragma unroll
                for (int m = 1; m < 32; m <<= 1) d2 += __shfl_xor(d2, m);
                if ((tid & 31) == 0) csqS[i >> 5] = d2;
            }
        }
        {   // stage F-tile: 64 anchors x 128 floats, coalesced, linear LDS
            const float4* Fb4 = (const float4*)(F + (size_t)(bxw * 64) * D_);
            float4* Ft4 = (float4*)Ft;
            #pragma unroll
            for (int it = 0; it < 4; ++it) {
                int i = it * 512 + tid;
                Ft4[i] = Fb4[i];
            }
        }
        __syncthreads();

        int lane = tid & 63;
        int wid = __builtin_amdgcn_readfirstlane(tid) >> 6;   // 0..7
        float csq = csqS[lane];
        float phv = phi[lane];
        int a0g = bxw * 64 + wid * 8;

        // phase B: centroid dots, lane = k; F via wave-uniform LDS b128
        const float4* FtW = (const float4*)(Ft + (wid * 8) * D_);
        float facc[8];
        #pragma unroll
        for (int j = 0; j < 8; ++j) facc[j] = 0.f;
        for (int dq = 0; dq < 32; ++dq) {
            int cbase = lane * 129 + (dq << 2);
            float cv0 = Cs[cbase + 0];
            float cv1 = Cs[cbase + 1];
            float cv2 = Cs[cbase + 2];
            float cv3 = Cs[cbase + 3];
            #pragma unroll
            for (int j = 0; j < 8; ++j) {
                float4 fb = FtW[j * 32 + dq];   // uniform addr -> broadcast
                facc[j] = fmaf(fb.x, cv0, fmaf(fb.y, cv1,
                          fmaf(fb.z, cv2, fmaf(fb.w, cv3, facc[j]))));
            }
        }

        // sq self-dot: 8 lanes per anchor, from LDS tile
        int j_of = lane >> 3, q = lane & 7;
        const float4* frL = (const float4*)(Ft + (wid * 8 + j_of) * D_);
        float sq_p = 0.f;
        #pragma unroll
        for (int i = 0; i < 4; ++i) {
            float4 fv = frL[i * 8 + q];
            sq_p = fmaf(fv.x, fv.x, fmaf(fv.y, fv.y, fmaf(fv.z, fv.z, fmaf(fv.w, fv.w, sq_p))));
        }
        #pragma unroll
        for (int m = 1; m < 8; m <<= 1) sq_p += __shfl_xor(sq_p, m);

        int lbl_p = L[a0g + j_of];

        // per-anchor cd2 -> s_cd, pos_cent; store {sq, s_cd, pc}
        #pragma unroll
        for (int j = 0; j < 8; ++j) {
            float sq_j = __shfl(sq_p, j * 8);
            int lbl_j = __shfl(lbl_p, j * 8);
            float cd2 = (sq_j + csq - 2.f * facc[j]) * (1.f / D_);
            cd2 = fmaxf(cd2, 0.f) / phv;
            float s_cd = cd2;
            #pragma unroll
            for (int m = 1; m < 64; m <<= 1) s_cd += __shfl_xor(s_cd, m);
            float pc = __shfl(cd2, lbl_j);
            if (lane == 0) {
                float* pp = pre + (size_t)(a0g + j) * 3;
                pp[0] = sq_j; pp[1] = s_cd; pp[2] = pc;
            }
        }
    } else {
        // ================= k1' : 2 classes per block =================
        __shared__ float redF[2][4][128];
        __shared__ float redS[2][4];
        __shared__ int   redC[2][4];
        int jb = blockIdx.x - 256;
        int b = jb & 7;                 // XCD-matched batch
        int cp = jb >> 3;               // class pair 0..31
        int lane = tid & 63;
        int wv = tid >> 6;
        int g = wv >> 2;                // 0/1: which class of the pair
        int k = cp * 2 + g;
        int wg = wv & 3;                // wave within class group

        const int* Lb = L + b * S_;
        const float* Fb = F + (size_t)b * S_ * D_;

        float a0 = 0.f, a1 = 0.f, q0 = 0.f, q1 = 0.f;
        int cnt = 0;
        #pragma unroll
        for (int rr = 0; rr < 8; ++rr) {
            int r = (wg << 3) + rr;
            int lbl = Lb[(r << 6) + lane];
            unsigned long long m = __ballot(lbl == k);
            cnt += (int)__popcll(m);
            while (m) {               // wave-uniform trip count
                int i = __ffsll((long long)m) - 1;
                m &= m - 1;
                const float* row = Fb + (size_t)((r << 6) + i) * D_;
                float v0 = row[lane];
                float v1 = row[64 + lane];
                a0 += v0; q0 = fmaf(v0, v0, q0);
                a1 += v1; q1 = fmaf(v1, v1, q1);
            }
        }
        float qq = q0 + q1;
        #pragma unroll
        for (int m = 1; m < 64; m <<= 1) qq += __shfl_xor(qq, m);
        redF[g][wg][lane] = a0;
        redF[g][wg][64 + lane] = a1;
        if (lane == 0) { redS[g][wg] = qq; redC[g][wg] = cnt; }
        __syncthreads();

        if (tid < 256) {
            int g2 = tid >> 7, d = tid & 127;
            float s = (redF[g2][0][d] + redF[g2][1][d]) + (redF[g2][2][d] + redF[g2][3][d]);
            fsumK[(size_t)(b * K_ + cp * 2 + g2) * D_ + d] = s;
            if (d == 0) {
                ssumK[b * K_ + cp * 2 + g2] =
                    (redS[g2][0] + redS[g2][1]) + (redS[g2][2] + redS[g2][3]);
                cntK[b * K_ + cp * 2 + g2] =
                    (float)(redC[g2][0] + redC[g2][1] + redC[g2][2] + redC[g2][3]);
            }
        }
    }
}

// ---------------- K_post: dk/da dots + light epilogue (256 blocks x 512 thr)
// Finish: one fire-and-forget HW f32 atomic add per block into out[0]
// (relaxed, no return, no acquire -> no R13/R16-style serialization stall).
__global__ void __launch_bounds__(512) k_post(
    const float* __restrict__ F, const int* __restrict__ L,
    const float* __restrict__ fsumK, const float* __restrict__ ssumK,
    const float* __restrict__ cntK, const float* __restrict__ pre,
    float* __restrict__ out) {

    __shared__ float4 redA[256];
    __shared__ float Fa[D_];
    __shared__ float wacc[8];
    int tid = threadIdx.x;
    int bxw = remap256(blockIdx.x);
    int b = bxw >> 5;

    if (tid < 256) {   // Fa[d] = sum_k fsumK[b,k,d]
        int d4 = tid & 31, kg = tid >> 5;
        const float4* g4 = (const float4*)(fsumK + (size_t)b * K_ * D_) + (size_t)kg * 8 * 32 + d4;
        float4 s; s.x = s.y = s.z = s.w = 0.f;
        #pragma unroll
        for (int kk = 0; kk < 8; ++kk) {
            float4 v = g4[(size_t)kk * 32];
            s.x += v.x; s.y += v.y; s.z += v.z; s.w += v.w;
        }
        redA[tid] = s;
    }
    __syncthreads();
    if (tid < 32) {
        float4 a; a.x = a.y = a.z = a.w = 0.f;
        #pragma unroll
        for (int g = 0; g < 8; ++g) {
            float4 v = redA[g * 32 + tid];
            a.x += v.x; a.y += v.y; a.z += v.z; a.w += v.w;
        }
        ((float4*)Fa)[tid] = a;
    }
    __syncthreads();

    int lane = tid & 63;
    float ssl = ssumK[b * K_ + lane];
    float cnl = cntK[b * K_ + lane];
    float ssA = ssl;
    #pragma unroll
    for (int m = 1; m < 64; m <<= 1) ssA += __shfl_xor(ssA, m);

    int wid = __builtin_amdgcn_readfirstlane(tid) >> 6;   // 0..7
    int a0g = bxw * 64 + wid * 8;
    const float4* F4 = (const float4*)F;

    int j_of = lane >> 3, q = lane & 7;
    int a_mine = a0g + j_of;
    int lbl_p = L[a_mine];
    const float4* fr = F4 + (size_t)a_mine * 32;
    const float4* fk = (const float4*)(fsumK + (size_t)(b * K_ + lbl_p) * D_);
    const float4* fa4 = (const float4*)Fa;

    float dk_p = 0.f, da_p = 0.f;
    #pragma unroll
    for (int i = 0; i < 4; ++i) {
        int dq = i * 8 + q;
        float4 fv = fr[dq];
        float4 kv = fk[dq];
        float4 av = fa4[dq];
        dk_p = fmaf(fv.x, kv.x, fmaf(fv.y, kv.y, fmaf(fv.z, kv.z, fmaf(fv.w, kv.w, dk_p))));
        da_p = fmaf(fv.x, av.x, fmaf(fv.y, av.y, fmaf(fv.z, av.z, fmaf(fv.w, av.w, da_p))));
    }
    #pragma unroll
    for (int m = 1; m < 8; m <<= 1) {
        dk_p += __shfl_xor(dk_p, m);
        da_p += __shfl_xor(da_p, m);
    }

    // pre values for this wave's 8 anchors: lanes 0..23 hold them
    float prev = (lane < 24) ? pre[(size_t)a0g * 3 + lane] : 0.f;

    float acc = 0.f;
    #pragma unroll
    for (int j = 0; j < 8; ++j) {
        float sq_j  = __shfl(prev, j * 3 + 0);
        float scd_j = __shfl(prev, j * 3 + 1);
        float pc_j  = __shfl(prev, j * 3 + 2);
        float dk_j = __shfl(dk_p, j * 8);
        float da_j = __shfl(da_p, j * 8);
        int lbl_j = __shfl(lbl_p, j * 8);
        float cnt_j = __shfl(cnl, lbl_j);
        float ssm_j = __shfl(ssl, lbl_j);

        float ncx = (scd_j - pc_j) * (1.f / (K_ - 1));
        float S_same = (cnt_j * sq_j + ssm_j - 2.f * dk_j) * (1.f / D_);
        float S_all = ((float)S_ * sq_j + ssA - 2.f * da_j) * (1.f / D_);
        float pos_x = fmaxf(S_same, 0.f) / fmaxf(cnt_j - 1.f, 1.f);
        float neg_cnt = (float)S_ - cnt_j;
        float neg_x = fmaxf(S_all - S_same, 0.f) / fmaxf(neg_cnt, 1.f);

        float neg_sup = neg_x * __logf(neg_x + E_);
        float ncl = ncx * __logf(ncx + E_);

        float pa = SIG_ * pos_x + (1.f - SIG_) * pc_j
                 - (SIG_ * neg_sup + (1.f - SIG_) * ncl) + EPS_;
        if (neg_cnt > 0.5f) acc += pa;
    }

    if (lane == 0) wacc[wid] = acc;
    __syncthreads();

    if (tid == 0) {
        float s = 0.f;
        #pragma unroll
        for (int w = 0; w < 8; ++w) s += wacc[w];
        unsafeAtomicAdd(out, s * (1.0f / (float)S_));   // global_atomic_add_f32
    }
}

extern "C" void kernel_launch(void* const* d_in, const int* in_sizes, int n_in,
                              void* d_out, int out_size, void* d_ws, size_t ws_size,
                              hipStream_t stream) {
    const float* F = (const float*)d_in[0];    // [B,S,D]
    const float* C = (const float*)d_in[1];    // [K,D]
    const float* phi = (const float*)d_in[2];  // [K]
    const int* L = (const int*)d_in[3];        // [B,S]
    float* out = (float*)d_out;

    float* ws = (float*)d_ws;
    float* fsumK = ws;                                // B*K*D = 65536
    float* ssumK = fsumK + (size_t)B_ * K_ * D_;      // 512
    float* cntK  = ssumK + B_ * K_;                   // 512
    float* pre = cntK + B_ * K_;                      // 16384*3 = 49152

    fused1<<<512, 512, 0, stream>>>(F, C, phi, L, fsumK, ssumK, cntK, pre, out);
    k_post<<<256, 512, 0, stream>>>(F, L, fsumK, ssumK, cntK, pre, out);
}

// Round 20
// 23.680 us; speedup vs baseline: 1.0613x; 1.0613x over previous
//
#include <hip/hip_runtime.h>
#include <math.h>

#define B_ 8
#define S_ 2048
#define D_ 128
#define K_ 64
#define SIG_ 0.5f
#define EPS_ 10.0f
#define E_ 2.718281828459045f

// XCD-aware remaps: HW round-robins blockIdx over 8 XCDs; batch == XCD.
__device__ __forceinline__ int remap256(int bx) { return ((bx & 7) << 5) | (bx >> 3); }

// ---------------- Fused dispatch 1: 512 blocks x 512 threads.
// Blocks 0..255  (kpre): k1-INDEPENDENT heavy half of the per-anchor kernel:
//   stage Cs+Ft (+co-op csq), phase B centroid GEMM, sq self-dot, and the
//   cd2 -> {s_cd, pos_cent} reduction; writes pre[a] = {sq, s_cd, pos_cent}.
// Blocks 256..511 (k1'): class stats for 2 classes per block (ballot+gather).
// The two families write disjoint buffers and need no mutual ordering.
__global__ void __launch_bounds__(512) fused1(
    const float* __restrict__ F, const float* __restrict__ C,
    const float* __restrict__ phi, const int* __restrict__ L,
    float* __restrict__ fsumK, float* __restrict__ ssumK, float* __restrict__ cntK,
    float* __restrict__ pre) {

    int tid = threadIdx.x;

    if (blockIdx.x < 256) {
        // ================= kpre =================
        __shared__ float Cs[K_ * 129];   // conflict-free b32 column reads
        __shared__ float Ft[64 * D_];    // block 64-anchor F-tile
        __shared__ float csqS[K_];
        int bxw = remap256(blockIdx.x);

        {   // stage centroids + co-op csq (32-thread groups share a centroid)
            const float4* C4 = (const float4*)C;
            #pragma unroll
            for (int it = 0; it < 4; ++it) {
                int i = it * 512 + tid;
                float4 v = C4[i];
                float* p = &Cs[(i >> 5) * 129 + ((i & 31) << 2)];
                p[0] = v.x; p[1] = v.y; p[2] = v.z; p[3] = v.w;
                float d2 = fmaf(v.x, v.x, fmaf(v.y, v.y, fmaf(v.z, v.z, v.w * v.w)));
                #pragma unroll
                for (int m = 1; m < 32; m <<= 1) d2 += __shfl_xor(d2, m);
                if ((tid & 31) == 0) csqS[i >> 5] = d2;
            }
        }
        {   // stage F-tile: 64 anchors x 128 floats, coalesced, linear LDS
            const float4* Fb4 = (const float4*)(F + (size_t)(bxw * 64) * D_);
            float4* Ft4 = (float4*)Ft;
            #pragma unroll
            for (int it = 0; it < 4; ++it) {
                int i = it * 512 + tid;
                Ft4[i] = Fb4[i];
            }
        }
        __syncthreads();

        int lane = tid & 63;
        int wid = __builtin_amdgcn_readfirstlane(tid) >> 6;   // 0..7
        float csq = csqS[lane];
        float phv = phi[lane];
        int a0g = bxw * 64 + wid * 8;

        // phase B: centroid dots, lane = k; F via wave-uniform LDS b128
        const float4* FtW = (const float4*)(Ft + (wid * 8) * D_);
        float facc[8];
        #pragma unroll
        for (int j = 0; j < 8; ++j) facc[j] = 0.f;
        for (int dq = 0; dq < 32; ++dq) {
            int cbase = lane * 129 + (dq << 2);
            float cv0 = Cs[cbase + 0];
            float cv1 = Cs[cbase + 1];
            float cv2 = Cs[cbase + 2];
            float cv3 = Cs[cbase + 3];
            #pragma unroll
            for (int j = 0; j < 8; ++j) {
                float4 fb = FtW[j * 32 + dq];   // uniform addr -> broadcast
                facc[j] = fmaf(fb.x, cv0, fmaf(fb.y, cv1,
                          fmaf(fb.z, cv2, fmaf(fb.w, cv3, facc[j]))));
            }
        }

        // sq self-dot: 8 lanes per anchor, from LDS tile
        int j_of = lane >> 3, q = lane & 7;
        const float4* frL = (const float4*)(Ft + (wid * 8 + j_of) * D_);
        float sq_p = 0.f;
        #pragma unroll
        for (int i = 0; i < 4; ++i) {
            float4 fv = frL[i * 8 + q];
            sq_p = fmaf(fv.x, fv.x, fmaf(fv.y, fv.y, fmaf(fv.z, fv.z, fmaf(fv.w, fv.w, sq_p))));
        }
        #pragma unroll
        for (int m = 1; m < 8; m <<= 1) sq_p += __shfl_xor(sq_p, m);

        int lbl_p = L[a0g + j_of];

        // per-anchor cd2 -> s_cd, pos_cent; store {sq, s_cd, pc}
        #pragma unroll
        for (int j = 0; j < 8; ++j) {
            float sq_j = __shfl(sq_p, j * 8);
            int lbl_j = __shfl(lbl_p, j * 8);
            float cd2 = (sq_j + csq - 2.f * facc[j]) * (1.f / D_);
            cd2 = fmaxf(cd2, 0.f) / phv;
            float s_cd = cd2;
            #pragma unroll
            for (int m = 1; m < 64; m <<= 1) s_cd += __shfl_xor(s_cd, m);
            float pc = __shfl(cd2, lbl_j);
            if (lane == 0) {
                float* pp = pre + (size_t)(a0g + j) * 3;
                pp[0] = sq_j; pp[1] = s_cd; pp[2] = pc;
            }
        }
    } else {
        // ================= k1' : 2 classes per block =================
        __shared__ float redF[2][4][128];
        __shared__ float redS[2][4];
        __shared__ int   redC[2][4];
        int jb = blockIdx.x - 256;
        int b = jb & 7;                 // XCD-matched batch
        int cp = jb >> 3;               // class pair 0..31
        int lane = tid & 63;
        int wv = tid >> 6;
        int g = wv >> 2;                // 0/1: which class of the pair
        int k = cp * 2 + g;
        int wg = wv & 3;                // wave within class group

        const int* Lb = L + b * S_;
        const float* Fb = F + (size_t)b * S_ * D_;

        float a0 = 0.f, a1 = 0.f, q0 = 0.f, q1 = 0.f;
        int cnt = 0;
        #pragma unroll
        for (int rr = 0; rr < 8; ++rr) {
            int r = (wg << 3) + rr;
            int lbl = Lb[(r << 6) + lane];
            unsigned long long m = __ballot(lbl == k);
            cnt += (int)__popcll(m);
            while (m) {               // wave-uniform trip count
                int i = __ffsll((long long)m) - 1;
                m &= m - 1;
                const float* row = Fb + (size_t)((r << 6) + i) * D_;
                float v0 = row[lane];
                float v1 = row[64 + lane];
                a0 += v0; q0 = fmaf(v0, v0, q0);
                a1 += v1; q1 = fmaf(v1, v1, q1);
            }
        }
        float qq = q0 + q1;
        #pragma unroll
        for (int m = 1; m < 64; m <<= 1) qq += __shfl_xor(qq, m);
        redF[g][wg][lane] = a0;
        redF[g][wg][64 + lane] = a1;
        if (lane == 0) { redS[g][wg] = qq; redC[g][wg] = cnt; }
        __syncthreads();

        if (tid < 256) {
            int g2 = tid >> 7, d = tid & 127;
            float s = (redF[g2][0][d] + redF[g2][1][d]) + (redF[g2][2][d] + redF[g2][3][d]);
            fsumK[(size_t)(b * K_ + cp * 2 + g2) * D_ + d] = s;
            if (d == 0) {
                ssumK[b * K_ + cp * 2 + g2] =
                    (redS[g2][0] + redS[g2][1]) + (redS[g2][2] + redS[g2][3]);
                cntK[b * K_ + cp * 2 + g2] =
                    (float)(redC[g2][0] + redC[g2][1] + redC[g2][2] + redC[g2][3]);
            }
        }
    }
}

// ---------------- K_post: dk/da dots + light epilogue (256 blocks x 512 thr)
__global__ void __launch_bounds__(512) k_post(
    const float* __restrict__ F, const int* __restrict__ L,
    const float* __restrict__ fsumK, const float* __restrict__ ssumK,
    const float* __restrict__ cntK, const float* __restrict__ pre,
    float* __restrict__ partial) {

    __shared__ float4 redA[256];
    __shared__ float Fa[D_];
    __shared__ float wacc[8];
    int tid = threadIdx.x;
    int bxw = remap256(blockIdx.x);
    int b = bxw >> 5;

    if (tid < 256) {   // Fa[d] = sum_k fsumK[b,k,d]
        int d4 = tid & 31, kg = tid >> 5;
        const float4* g4 = (const float4*)(fsumK + (size_t)b * K_ * D_) + (size_t)kg * 8 * 32 + d4;
        float4 s; s.x = s.y = s.z = s.w = 0.f;
        #pragma unroll
        for (int kk = 0; kk < 8; ++kk) {
            float4 v = g4[(size_t)kk * 32];
            s.x += v.x; s.y += v.y; s.z += v.z; s.w += v.w;
        }
        redA[tid] = s;
    }
    __syncthreads();
    if (tid < 32) {
        float4 a; a.x = a.y = a.z = a.w = 0.f;
        #pragma unroll
        for (int g = 0; g < 8; ++g) {
            float4 v = redA[g * 32 + tid];
            a.x += v.x; a.y += v.y; a.z += v.z; a.w += v.w;
        }
        ((float4*)Fa)[tid] = a;
    }
    __syncthreads();

    int lane = tid & 63;
    float ssl = ssumK[b * K_ + lane];
    float cnl = cntK[b * K_ + lane];
    float ssA = ssl;
    #pragma unroll
    for (int m = 1; m < 64; m <<= 1) ssA += __shfl_xor(ssA, m);

    int wid = __builtin_amdgcn_readfirstlane(tid) >> 6;   // 0..7
    int a0g = bxw * 64 + wid * 8;
    const float4* F4 = (const float4*)F;

    int j_of = lane >> 3, q = lane & 7;
    int a_mine = a0g + j_of;
    int lbl_p = L[a_mine];
    const float4* fr = F4 + (size_t)a_mine * 32;
    const float4* fk = (const float4*)(fsumK + (size_t)(b * K_ + lbl_p) * D_);
    const float4* fa4 = (const float4*)Fa;

    float dk_p = 0.f, da_p = 0.f;
    #pragma unroll
    for (int i = 0; i < 4; ++i) {
        int dq = i * 8 + q;
        float4 fv = fr[dq];
        float4 kv = fk[dq];
        float4 av = fa4[dq];
        dk_p = fmaf(fv.x, kv.x, fmaf(fv.y, kv.y, fmaf(fv.z, kv.z, fmaf(fv.w, kv.w, dk_p))));
        da_p = fmaf(fv.x, av.x, fmaf(fv.y, av.y, fmaf(fv.z, av.z, fmaf(fv.w, av.w, da_p))));
    }
    #pragma unroll
    for (int m = 1; m < 8; m <<= 1) {
        dk_p += __shfl_xor(dk_p, m);
        da_p += __shfl_xor(da_p, m);
    }

    // pre values for this wave's 8 anchors: lanes 0..23 hold them
    float prev = (lane < 24) ? pre[(size_t)a0g * 3 + lane] : 0.f;

    float acc = 0.f;
    #pragma unroll
    for (int j = 0; j < 8; ++j) {
        float sq_j  = __shfl(prev, j * 3 + 0);
        float scd_j = __shfl(prev, j * 3 + 1);
        float pc_j  = __shfl(prev, j * 3 + 2);
        float dk_j = __shfl(dk_p, j * 8);
        float da_j = __shfl(da_p, j * 8);
        int lbl_j = __shfl(lbl_p, j * 8);
        float cnt_j = __shfl(cnl, lbl_j);
        float ssm_j = __shfl(ssl, lbl_j);

        float ncx = (scd_j - pc_j) * (1.f / (K_ - 1));
        float S_same = (cnt_j * sq_j + ssm_j - 2.f * dk_j) * (1.f / D_);
        float S_all = ((float)S_ * sq_j + ssA - 2.f * da_j) * (1.f / D_);
        float pos_x = fmaxf(S_same, 0.f) / fmaxf(cnt_j - 1.f, 1.f);
        float neg_cnt = (float)S_ - cnt_j;
        float neg_x = fmaxf(S_all - S_same, 0.f) / fmaxf(neg_cnt, 1.f);

        float neg_sup = neg_x * __logf(neg_x + E_);
        float ncl = ncx * __logf(ncx + E_);

        float pa = SIG_ * pos_x + (1.f - SIG_) * pc_j
                 - (SIG_ * neg_sup + (1.f - SIG_) * ncl) + EPS_;
        if (neg_cnt > 0.5f) acc += pa;
    }

    if (lane == 0) wacc[wid] = acc;
    __syncthreads();

    // plain-store finish (no atomics) — proven R13/R15/R17/R18
    if (tid == 0) {
        float s = 0.f;
        #pragma unroll
        for (int w = 0; w < 8; ++w) s += wacc[w];
        partial[bxw] = s;
    }
}

// ---------------- K4: 1-block final reduce (256 partials)
__global__ void __launch_bounds__(256) k4_reduce(
    const float* __restrict__ partial, float* __restrict__ out) {
    int tid = threadIdx.x;
    int lane = tid & 63;
    int wv = tid >> 6;
    __shared__ float w[4];
    float v = partial[tid];
    #pragma unroll
    for (int m = 1; m < 64; m <<= 1) v += __shfl_xor(v, m);
    if (lane == 0) w[wv] = v;
    __syncthreads();
    if (tid == 0) out[0] = (w[0] + w[1] + w[2] + w[3]) * (1.0f / (float)S_);
}

extern "C" void kernel_launch(void* const* d_in, const int* in_sizes, int n_in,
                              void* d_out, int out_size, void* d_ws, size_t ws_size,
                              hipStream_t stream) {
    const float* F = (const float*)d_in[0];    // [B,S,D]
    const float* C = (const float*)d_in[1];    // [K,D]
    const float* phi = (const float*)d_in[2];  // [K]
    const int* L = (const int*)d_in[3];        // [B,S]
    float* out = (float*)d_out;

    float* ws = (float*)d_ws;
    float* fsumK = ws;                                // B*K*D = 65536
    float* ssumK = fsumK + (size_t)B_ * K_ * D_;      // 512
    float* cntK  = ssumK + B_ * K_;                   // 512
    float* partial = cntK + B_ * K_;                  // 256
    float* pre = partial + 256;                       // 16384*3 = 49152

    fused1<<<512, 512, 0, stream>>>(F, C, phi, L, fsumK, ssumK, cntK, pre);
    k_post<<<256, 512, 0, stream>>>(F, L, fsumK, ssumK, cntK, pre, partial);
    k4_reduce<<<1, 256, 0, stream>>>(partial, out);
}